// Round 12
// baseline (7319.427 us; speedup 1.0000x reference)
//
#include <hip/hip_runtime.h>

typedef unsigned int uint;
typedef unsigned short ushort_t;

#define NB 512      // batch
#define NK 1152     // input capsules
#define ND 8        // in dim
#define NU 16       // out dim
#define NJ 10       // output capsules
#define NPH 30      // routing phases (NJ * 3)
#define EPSQ 1e-7f

#define KT 36       // k per tile
#define KCN 32      // k chunks; kc = blockIdx&31 -> XCD = kc%8
#define BT 16       // b per tile
#define BGN 32      // b groups
#define NBLK (KCN * BGN)  // 1024 = exactly 4 blocks/CU
#define XPH 296     // x tile pitch per b (bf16 elems)
#define WPH 136     // w tile pitch per k (bf16 elems)
#define SREDP 20    // cross-wave reduce pitch (floats)
#define SVP 20      // sv pitch (floats)

// ws layout (floats)
#define OFF_BL 0                        // b_logits [NK][NJ]      11520
#define OFF_S  11520                    // s [NPH][NB][NU]        245760
#define OFF_BAR 257280                  // barrier counter (1 int) + pad
#define OFF_XB 257344                   // Xb bf16 [NB][NK][ND]
#define OFF_WTB (OFF_XB + (NB*NK*ND)/2) // WTb bf16 [NJ][NK][NU][ND]

// fp32 -> bf16 RNE
__device__ __forceinline__ ushort_t b16(float f) {
  uint u = __float_as_uint(f);
  return (ushort_t)((u + 0x7fffu + ((u >> 16) & 1u)) >> 16);
}
__device__ __forceinline__ void up8(const uint4 v, float* f) {
  f[0] = __uint_as_float(v.x << 16); f[1] = __uint_as_float(v.x & 0xffff0000u);
  f[2] = __uint_as_float(v.y << 16); f[3] = __uint_as_float(v.y & 0xffff0000u);
  f[4] = __uint_as_float(v.z << 16); f[5] = __uint_as_float(v.z & 0xffff0000u);
  f[6] = __uint_as_float(v.w << 16); f[7] = __uint_as_float(v.w & 0xffff0000u);
}
__device__ __forceinline__ float dot8(const float* a, const float* b) {
  return a[0]*b[0] + a[1]*b[1] + a[2]*b[2] + a[3]*b[3] +
         a[4]*b[4] + a[5]*b[5] + a[6]*b[6] + a[7]*b[7];
}
// agent-scope load: reads the LLC coherence point (sees remote XCD atomics)
__device__ __forceinline__ float aload(const float* p) {
  return __hip_atomic_load(p, __ATOMIC_RELAXED, __HIP_MEMORY_SCOPE_AGENT);
}

// ---------------------------------------------------------------------------
// init: zero bl + s + barrier; build Xb, WTb (bf16)
// ---------------------------------------------------------------------------
__global__ __launch_bounds__(256) void caps_init(const float* __restrict__ x,
                                                 const float* __restrict__ W,
                                                 float* __restrict__ bl,
                                                 float* __restrict__ s,
                                                 int* __restrict__ bar,
                                                 ushort_t* __restrict__ Xb,
                                                 ushort_t* __restrict__ WTb) {
  const int g = blockIdx.x * 256 + threadIdx.x;
  if (g == 0) *bar = 0;
  if (g < NK * NJ) bl[g] = 0.f;
  if (g < NPH * NB * NU) s[g] = 0.f;
  if (g < (NB * NK * ND) / 8) {
    const float4* xp = (const float4*)x + (size_t)g * 2;
    const float4 a = xp[0], b = xp[1];
    uint4 o;
    o.x = (uint)b16(a.x) | ((uint)b16(a.y) << 16);
    o.y = (uint)b16(a.z) | ((uint)b16(a.w) << 16);
    o.z = (uint)b16(b.x) | ((uint)b16(b.y) << 16);
    o.w = (uint)b16(b.z) | ((uint)b16(b.w) << 16);
    ((uint4*)Xb)[g] = o;
  }
  if (g < (NJ * NK * NU * ND) / 8) {
    const int u = g & 15;
    const int k = (g >> 4) % NK;
    const int j = g / (NK * NU);
    const float* wp = W + ((size_t)(j * NK + k) * ND) * NU + u;
    uint4 o;
    o.x = (uint)b16(wp[0])  | ((uint)b16(wp[16]) << 16);
    o.y = (uint)b16(wp[32]) | ((uint)b16(wp[48]) << 16);
    o.z = (uint)b16(wp[64]) | ((uint)b16(wp[80]) << 16);
    o.w = (uint)b16(wp[96]) | ((uint)b16(wp[112]) << 16);
    ((uint4*)WTb)[g] = o;
  }
}

// ===========================================================================
// PERSISTENT cooperative kernel: all 30 phases, custom lightweight barrier.
// Block (kc,bgi): x tile LDS-staged ONCE; W[j] staged once per capsule.
// ===========================================================================
__global__ __launch_bounds__(256, 4) void caps_persist(
    const ushort_t* __restrict__ Xb, const ushort_t* __restrict__ WTb,
    float* __restrict__ bl, float* __restrict__ s, float* __restrict__ out,
    int* __restrict__ bar) {
  __shared__ __align__(16) ushort_t sxu[BT * XPH];   // 9472 B
  __shared__ __align__(16) ushort_t swu[KT * WPH];   // 9792 B
  __shared__ float sc[KT];
  __shared__ float sred[4 * BT * SREDP];             // 5120 B
  __shared__ float sv[BT * SVP];                     // 1280 B  (total ~25.8 KB)
  const int tid = threadIdx.x;
  const int kc = blockIdx.x & (KCN - 1);
  const int bgi = blockIdx.x >> 5;
  const int b0 = bgi * BT;
  const int k0 = kc * KT;

  {  // stage x ONCE
    const uint4* gx = (const uint4*)Xb + ((size_t)b0 * NK + k0);
    for (int i = tid; i < BT * KT; i += 256) {
      const int b = i / KT, q = i - b * KT;
      *(uint4*)&sxu[b * XPH + q * 8] = gx[(size_t)b * NK + q];
    }
  }
  {  // stage W[0]
    const uint4* gw = (const uint4*)WTb + (size_t)k0 * NU;
    for (int i = tid; i < KT * NU; i += 256) {
      const int k = i >> 4, u = i & 15;
      *(uint4*)&swu[k * WPH + u * 8] = gw[i];
    }
  }

  const int w = tid >> 6;
  const int lane = tid & 63;
  const int kq = lane >> 4;
  const int bq = (lane >> 2) & 3;
  const int uq = lane & 3;
  int gen = 0;

  for (int n = 0; n < NPH; ++n) {
    const int j = n / 3, t = n - 3 * j;
    if (n > 0) {
      const int ja = (t == 0) ? (j - 1) : j;
      {  // v = squash(s[n-1]) -- scoped loads see all blocks' atomics
        const int b = tid >> 4, u = tid & 15;
        const float sval = aload(&s[(size_t)(n - 1) * NB * NU +
                                    (size_t)(b0 + b) * NU + u]);
        float sq = sval * sval;
        sq += __shfl_xor(sq, 1, 64);
        sq += __shfl_xor(sq, 2, 64);
        sq += __shfl_xor(sq, 4, 64);
        sq += __shfl_xor(sq, 8, 64);
        const float scale = (sq / (1.f + sq)) / (sqrtf(sq) + EPSQ);
        const float vv = scale * sval;
        sv[b * SVP + u] = vv;
        if (t == 0 && kc == 0)  // final v of capsule j-1
          out[((size_t)(b0 + b) * NJ + ja) * NU + u] = vv;
      }
      __syncthreads();
      {  // agree for column ja (swu still holds W[ja])
        float4 vf[4];
#pragma unroll
        for (int i = 0; i < 4; ++i)
          vf[i] = *(const float4*)&sv[(bq * 4 + i) * SVP + uq * 4];
#pragma unroll
        for (int it = 0; it < 3; ++it) {
          const int kli = it * 4 + kq;
          if (kli < 9) {
            const int kl = w * 9 + kli;
            float xd[4][8];
#pragma unroll
            for (int i = 0; i < 4; ++i)
              up8(*(const uint4*)&sxu[(bq * 4 + i) * XPH + kl * 8], xd[i]);
            float ag = 0.f;
#pragma unroll
            for (int m = 0; m < 4; ++m) {
              float wd[8];
              up8(*(const uint4*)&swu[kl * WPH + (uq * 4 + m) * 8], wd);
#pragma unroll
              for (int i = 0; i < 4; ++i) {
                const float vm = (m == 0) ? vf[i].x
                               : (m == 1) ? vf[i].y
                               : (m == 2) ? vf[i].z : vf[i].w;
                ag = fmaf(vm, dot8(xd[i], wd), ag);
              }
            }
            ag += __shfl_xor(ag, 1, 64);
            ag += __shfl_xor(ag, 2, 64);
            ag += __shfl_xor(ag, 4, 64);
            ag += __shfl_xor(ag, 8, 64);
            if ((lane & 15) == 0)
              atomicAdd(&bl[(size_t)(k0 + kl) * NJ + ja], ag);
          }
        }
      }
      if (t == 0) {  // stage W[j] (all waves done reading swu)
        __syncthreads();
        const uint4* gw = (const uint4*)WTb + ((size_t)j * NK + k0) * NU;
        for (int i = tid; i < KT * NU; i += 256) {
          const int k = i >> 4, u = i & 15;
          *(uint4*)&swu[k * WPH + u * 8] = gw[i];
        }
      }
      {  // global barrier: agree(n) complete before softmax reads bl
        __syncthreads();
        if (tid == 0) {
          __hip_atomic_fetch_add(bar, 1, __ATOMIC_ACQ_REL,
                                 __HIP_MEMORY_SCOPE_AGENT);
          const int target = (++gen) * NBLK;
          while (__hip_atomic_load(bar, __ATOMIC_ACQUIRE,
                                   __HIP_MEMORY_SCOPE_AGENT) < target)
            __builtin_amdgcn_s_sleep(1);
        }
        __syncthreads();
      }
    }
    // ---- part phase: softmax col j, then s[n] += tile contraction ----
    if (tid < KT) {
      const float* row = bl + (size_t)(k0 + tid) * NJ;
      float r[NJ];
#pragma unroll
      for (int jj = 0; jj < NJ; ++jj) r[jj] = aload(&row[jj]);
      float mx = r[0];
#pragma unroll
      for (int jj = 1; jj < NJ; ++jj) mx = fmaxf(mx, r[jj]);
      float se = 0.f;
#pragma unroll
      for (int jj = 0; jj < NJ; ++jj) se += __expf(r[jj] - mx);
      sc[tid] = __expf(r[j] - mx) / se;
    }
    __syncthreads();
    float a[4][4];
#pragma unroll
    for (int i = 0; i < 4; ++i)
#pragma unroll
      for (int m = 0; m < 4; ++m) a[i][m] = 0.f;
#pragma unroll
    for (int it = 0; it < 3; ++it) {
      const int kli = it * 4 + kq;
      if (kli < 9) {
        const int kl = w * 9 + kli;
        const float ck = sc[kl];
        float xd[4][8];
#pragma unroll
        for (int i = 0; i < 4; ++i)
          up8(*(const uint4*)&sxu[(bq * 4 + i) * XPH + kl * 8], xd[i]);
#pragma unroll
        for (int m = 0; m < 4; ++m) {
          float wd[8];
          up8(*(const uint4*)&swu[kl * WPH + (uq * 4 + m) * 8], wd);
#pragma unroll
          for (int i = 0; i < 4; ++i)
            a[i][m] = fmaf(ck, dot8(xd[i], wd), a[i][m]);
        }
      }
    }
#pragma unroll
    for (int i = 0; i < 4; ++i)
#pragma unroll
      for (int m = 0; m < 4; ++m) {
        a[i][m] += __shfl_xor(a[i][m], 16, 64);
        a[i][m] += __shfl_xor(a[i][m], 32, 64);
      }
    __syncthreads();
    if (kq == 0) {
#pragma unroll
      for (int i = 0; i < 4; ++i) {
        const float4 t4 = {a[i][0], a[i][1], a[i][2], a[i][3]};
        *(float4*)&sred[(w * BT + bq * 4 + i) * SREDP + uq * 4] = t4;
      }
    }
    __syncthreads();
    {
      const int b = tid >> 4, u = tid & 15;
      const float sx4 =
          sred[(0 * BT + b) * SREDP + u] + sred[(1 * BT + b) * SREDP + u] +
          sred[(2 * BT + b) * SREDP + u] + sred[(3 * BT + b) * SREDP + u];
      atomicAdd(&s[(size_t)n * NB * NU + (size_t)(b0 + b) * NU + u], sx4);
    }
    {  // global barrier: part(n) complete before agree/final reads s[n]
      __syncthreads();
      if (tid == 0) {
        __hip_atomic_fetch_add(bar, 1, __ATOMIC_ACQ_REL,
                               __HIP_MEMORY_SCOPE_AGENT);
        const int target = (++gen) * NBLK;
        while (__hip_atomic_load(bar, __ATOMIC_ACQUIRE,
                                 __HIP_MEMORY_SCOPE_AGENT) < target)
          __builtin_amdgcn_s_sleep(1);
      }
      __syncthreads();
    }
  }
  if (kc == 0) {  // final v of capsule 9
    const int b = tid >> 4, u = tid & 15;
    const float sval =
        aload(&s[(size_t)(NPH - 1) * NB * NU + (size_t)(b0 + b) * NU + u]);
    float sq = sval * sval;
    sq += __shfl_xor(sq, 1, 64);
    sq += __shfl_xor(sq, 2, 64);
    sq += __shfl_xor(sq, 4, 64);
    sq += __shfl_xor(sq, 8, 64);
    const float scale = (sq / (1.f + sq)) / (sqrtf(sq) + EPSQ);
    out[((size_t)(b0 + b) * NJ + (NJ - 1)) * NU + u] = scale * sval;
  }
}

// ===========================================================================
// R11 fallback kernels (verified) — used only if cooperative launch fails.
// ===========================================================================
__global__ __launch_bounds__(256, 4) void caps_part(
    const ushort_t* __restrict__ Xb, const ushort_t* __restrict__ WTb,
    const float* __restrict__ bl, float* __restrict__ sn, int js) {
  __shared__ __align__(16) ushort_t sxu[BT * XPH];
  __shared__ __align__(16) ushort_t swu[KT * WPH];
  __shared__ float sc[KT];
  float* sred = (float*)sxu;
  const int tid = threadIdx.x;
  const int kc = blockIdx.x & (KCN - 1);
  const int bgi = blockIdx.x >> 5;
  const int b0 = bgi * BT;
  const int k0 = kc * KT;
  {
    const uint4* gx = (const uint4*)Xb + ((size_t)b0 * NK + k0);
    for (int i = tid; i < BT * KT; i += 256) {
      const int b = i / KT, q = i - b * KT;
      *(uint4*)&sxu[b * XPH + q * 8] = gx[(size_t)b * NK + q];
    }
  }
  {
    const uint4* gw = (const uint4*)WTb + ((size_t)js * NK + k0) * NU;
    for (int i = tid; i < KT * NU; i += 256) {
      const int k = i >> 4, u = i & 15;
      *(uint4*)&swu[k * WPH + u * 8] = gw[i];
    }
  }
  if (tid < KT) {
    const float* row = bl + (size_t)(k0 + tid) * NJ;
    float r[NJ];
#pragma unroll
    for (int jj = 0; jj < NJ; ++jj) r[jj] = row[jj];
    float mx = r[0];
#pragma unroll
    for (int jj = 1; jj < NJ; ++jj) mx = fmaxf(mx, r[jj]);
    float se = 0.f;
#pragma unroll
    for (int jj = 0; jj < NJ; ++jj) se += __expf(r[jj] - mx);
    sc[tid] = __expf(r[js] - mx) / se;
  }
  __syncthreads();
  const int w = tid >> 6;
  const int lane = tid & 63;
  const int kq = lane >> 4;
  const int bq = (lane >> 2) & 3;
  const int uq = lane & 3;
  float a[4][4];
#pragma unroll
  for (int i = 0; i < 4; ++i)
#pragma unroll
    for (int m = 0; m < 4; ++m) a[i][m] = 0.f;
#pragma unroll
  for (int it = 0; it < 3; ++it) {
    const int kli = it * 4 + kq;
    if (kli < 9) {
      const int kl = w * 9 + kli;
      const float ck = sc[kl];
      float xd[4][8];
#pragma unroll
      for (int i = 0; i < 4; ++i)
        up8(*(const uint4*)&sxu[(bq * 4 + i) * XPH + kl * 8], xd[i]);
#pragma unroll
      for (int m = 0; m < 4; ++m) {
        float wd[8];
        up8(*(const uint4*)&swu[kl * WPH + (uq * 4 + m) * 8], wd);
#pragma unroll
        for (int i = 0; i < 4; ++i)
          a[i][m] = fmaf(ck, dot8(xd[i], wd), a[i][m]);
      }
    }
  }
#pragma unroll
  for (int i = 0; i < 4; ++i)
#pragma unroll
    for (int m = 0; m < 4; ++m) {
      a[i][m] += __shfl_xor(a[i][m], 16, 64);
      a[i][m] += __shfl_xor(a[i][m], 32, 64);
    }
  __syncthreads();
  if (kq == 0) {
#pragma unroll
    for (int i = 0; i < 4; ++i) {
      const float4 t4 = {a[i][0], a[i][1], a[i][2], a[i][3]};
      *(float4*)&sred[(w * BT + bq * 4 + i) * SREDP + uq * 4] = t4;
    }
  }
  __syncthreads();
  {
    const int b = tid >> 4, u = tid & 15;
    const float sv =
        sred[(0 * BT + b) * SREDP + u] + sred[(1 * BT + b) * SREDP + u] +
        sred[(2 * BT + b) * SREDP + u] + sred[(3 * BT + b) * SREDP + u];
    atomicAdd(&sn[(size_t)(b0 + b) * NU + u], sv);
  }
}

__global__ __launch_bounds__(256, 4) void caps_agp(
    const ushort_t* __restrict__ Xb, const ushort_t* __restrict__ WTb,
    const float* __restrict__ sprev, float* __restrict__ bl,
    float* __restrict__ out, int ja, int wout) {
  __shared__ __align__(16) ushort_t sxu[BT * XPH];
  __shared__ __align__(16) ushort_t swu[KT * WPH];
  __shared__ float sv[BT * SVP];
  const int tid = threadIdx.x;
  const int kc = blockIdx.x & (KCN - 1);
  const int bgi = blockIdx.x >> 5;
  const int b0 = bgi * BT;
  const int k0 = kc * KT;
  {
    const uint4* gx = (const uint4*)Xb + ((size_t)b0 * NK + k0);
    for (int i = tid; i < BT * KT; i += 256) {
      const int b = i / KT, q = i - b * KT;
      *(uint4*)&sxu[b * XPH + q * 8] = gx[(size_t)b * NK + q];
    }
  }
  {
    const uint4* gw = (const uint4*)WTb + ((size_t)ja * NK + k0) * NU;
    for (int i = tid; i < KT * NU; i += 256) {
      const int k = i >> 4, u = i & 15;
      *(uint4*)&swu[k * WPH + u * 8] = gw[i];
    }
  }
  {
    const int b = tid >> 4, u = tid & 15;
    const float s = sprev[(size_t)(b0 + b) * NU + u];
    float sq = s * s;
    sq += __shfl_xor(sq, 1, 64);
    sq += __shfl_xor(sq, 2, 64);
    sq += __shfl_xor(sq, 4, 64);
    sq += __shfl_xor(sq, 8, 64);
    const float scale = (sq / (1.f + sq)) / (sqrtf(sq) + EPSQ);
    const float vv = scale * s;
    sv[b * SVP + u] = vv;
    if (wout && kc == 0) out[((size_t)(b0 + b) * NJ + ja) * NU + u] = vv;
  }
  __syncthreads();
  const int w = tid >> 6;
  const int lane = tid & 63;
  const int kq = lane >> 4;
  const int bq = (lane >> 2) & 3;
  const int uq = lane & 3;
  float4 vf[4];
#pragma unroll
  for (int i = 0; i < 4; ++i)
    vf[i] = *(const float4*)&sv[(bq * 4 + i) * SVP + uq * 4];
#pragma unroll
  for (int it = 0; it < 3; ++it) {
    const int kli = it * 4 + kq;
    if (kli < 9) {
      const int kl = w * 9 + kli;
      float xd[4][8];
#pragma unroll
      for (int i = 0; i < 4; ++i)
        up8(*(const uint4*)&sxu[(bq * 4 + i) * XPH + kl * 8], xd[i]);
      float ag = 0.f;
#pragma unroll
      for (int m = 0; m < 4; ++m) {
        float wd[8];
        up8(*(const uint4*)&swu[kl * WPH + (uq * 4 + m) * 8], wd);
#pragma unroll
        for (int i = 0; i < 4; ++i) {
          const float vm = (m == 0) ? vf[i].x
                         : (m == 1) ? vf[i].y
                         : (m == 2) ? vf[i].z : vf[i].w;
          ag = fmaf(vm, dot8(xd[i], wd), ag);
        }
      }
      ag += __shfl_xor(ag, 1, 64);
      ag += __shfl_xor(ag, 2, 64);
      ag += __shfl_xor(ag, 4, 64);
      ag += __shfl_xor(ag, 8, 64);
      if ((lane & 15) == 0)
        atomicAdd(&bl[(size_t)(k0 + kl) * NJ + ja], ag);
    }
  }
}

__global__ __launch_bounds__(256) void caps_finout(const float* __restrict__ slast,
                                                   float* __restrict__ out) {
  const int g = blockIdx.x * 256 + threadIdx.x;
  const int b = g >> 4, u = g & 15;
  const float s = slast[(size_t)b * NU + u];
  float sq = s * s;
  sq += __shfl_xor(sq, 1, 64);
  sq += __shfl_xor(sq, 2, 64);
  sq += __shfl_xor(sq, 4, 64);
  sq += __shfl_xor(sq, 8, 64);
  const float scale = (sq / (1.f + sq)) / (sqrtf(sq) + EPSQ);
  out[((size_t)b * NJ + (NJ - 1)) * NU + u] = scale * s;
}

// ---------------------------------------------------------------------------
extern "C" void kernel_launch(void* const* d_in, const int* in_sizes, int n_in,
                              void* d_out, int out_size, void* d_ws,
                              size_t ws_size, hipStream_t stream) {
  (void)in_sizes; (void)n_in; (void)out_size; (void)ws_size;
  const float* x = (const float*)d_in[0];   // [512][1152][8][1] fp32
  const float* W = (const float*)d_in[1];   // [10][1152][8][16] fp32
  float* out = (float*)d_out;               // [512][10][16][1] fp32
  float* ws = (float*)d_ws;
  float* bl = ws + OFF_BL;
  float* s  = ws + OFF_S;
  int* bar  = (int*)(ws + OFF_BAR);
  ushort_t* Xb  = (ushort_t*)(ws + OFF_XB);
  ushort_t* WTb = (ushort_t*)(ws + OFF_WTB);

  caps_init<<<(NB * NK * ND / 8 + 255) / 256, 256, 0, stream>>>(x, W, bl, s,
                                                                bar, Xb, WTb);
  void* args[] = {(void*)&Xb, (void*)&WTb, (void*)&bl, (void*)&s,
                  (void*)&out, (void*)&bar};
  hipError_t err = hipLaunchCooperativeKernel(
      (const void*)caps_persist, dim3(NBLK), dim3(256), args, 0, stream);
  if (err != hipSuccess) {
    (void)hipGetLastError();  // clear; verified R11 multi-kernel path
    for (int n = 0; n < NPH; ++n) {
      const int j = n / 3, t = n - 3 * j;
      if (n > 0) {
        const int ja = (t == 0) ? (j - 1) : j;
        caps_agp<<<KCN * BGN, 256, 0, stream>>>(
            Xb, WTb, s + (size_t)(n - 1) * NB * NU, bl, out, ja,
            (t == 0) ? 1 : 0);
      }
      caps_part<<<KCN * BGN, 256, 0, stream>>>(Xb, WTb, bl,
                                               s + (size_t)n * NB * NU, j);
    }
    caps_finout<<<(NB * NU) / 256, 256, 0, stream>>>(
        s + (size_t)(NPH - 1) * NB * NU, out);
  }
}

// Round 13
// 1202.966 us; speedup vs baseline: 6.0845x; 6.0845x over previous
//
#include <hip/hip_runtime.h>

typedef unsigned int uint;
typedef unsigned short ushort_t;

#define NB 512      // batch
#define NK 1152     // input capsules
#define ND 8        // in dim
#define NU 16       // out dim
#define NJ 10       // output capsules
#define NPH 30      // routing phases (NJ * 3)
#define EPSQ 1e-7f

#define KT 24       // k per tile (R13: 36->24 for 6 blocks/CU)
#define KCN 48      // k chunks (KT*KCN == NK); kc%8 == blockIdx%8 -> XCD slot
#define BT 16       // b per tile
#define BGN 32      // b groups
#define XPH 200     // x tile pitch per b, bf16 elems (192 + 8 pad; 2-way banks)
#define WPH 136     // w tile pitch per k, bf16 elems (128 + 8 pad; 2-way banks)
#define SREDP 20    // cross-wave reduce pitch (floats)
#define SVP 20      // sv pitch (floats)

// ws layout (floats)
#define OFF_BL 0                        // b_logits [NK][NJ]      11520
#define OFF_S  11520                    // s [NPH][NB][NU]        245760
#define OFF_XB 257280                   // Xb bf16 [NB][NK][ND]
#define OFF_WTB (OFF_XB + (NB*NK*ND)/2) // WTb bf16 [NJ][NK][NU][ND]

// fp32 -> bf16 RNE
__device__ __forceinline__ ushort_t b16(float f) {
  uint u = __float_as_uint(f);
  return (ushort_t)((u + 0x7fffu + ((u >> 16) & 1u)) >> 16);
}
__device__ __forceinline__ void up8(const uint4 v, float* f) {
  f[0] = __uint_as_float(v.x << 16); f[1] = __uint_as_float(v.x & 0xffff0000u);
  f[2] = __uint_as_float(v.y << 16); f[3] = __uint_as_float(v.y & 0xffff0000u);
  f[4] = __uint_as_float(v.z << 16); f[5] = __uint_as_float(v.z & 0xffff0000u);
  f[6] = __uint_as_float(v.w << 16); f[7] = __uint_as_float(v.w & 0xffff0000u);
}
__device__ __forceinline__ float dot8(const float* a, const float* b) {
  return a[0]*b[0] + a[1]*b[1] + a[2]*b[2] + a[3]*b[3] +
         a[4]*b[4] + a[5]*b[5] + a[6]*b[6] + a[7]*b[7];
}

// ---------------------------------------------------------------------------
// init: zero bl + s; build Xb[b][k][d], WTb[j][k][u][d] (bf16)
// ---------------------------------------------------------------------------
__global__ __launch_bounds__(256) void caps_init(const float* __restrict__ x,
                                                 const float* __restrict__ W,
                                                 float* __restrict__ bl,
                                                 float* __restrict__ s,
                                                 ushort_t* __restrict__ Xb,
                                                 ushort_t* __restrict__ WTb) {
  const int g = blockIdx.x * 256 + threadIdx.x;
  if (g < NK * NJ) bl[g] = 0.f;
  if (g < NPH * NB * NU) s[g] = 0.f;
  if (g < (NB * NK * ND) / 8) {
    const float4* xp = (const float4*)x + (size_t)g * 2;
    const float4 a = xp[0], b = xp[1];
    uint4 o;
    o.x = (uint)b16(a.x) | ((uint)b16(a.y) << 16);
    o.y = (uint)b16(a.z) | ((uint)b16(a.w) << 16);
    o.z = (uint)b16(b.x) | ((uint)b16(b.y) << 16);
    o.w = (uint)b16(b.z) | ((uint)b16(b.w) << 16);
    ((uint4*)Xb)[g] = o;
  }
  if (g < (NJ * NK * NU * ND) / 8) {
    const int u = g & 15;
    const int k = (g >> 4) % NK;
    const int j = g / (NK * NU);
    const float* wp = W + ((size_t)(j * NK + k) * ND) * NU + u;
    uint4 o;
    o.x = (uint)b16(wp[0])  | ((uint)b16(wp[16]) << 16);
    o.y = (uint)b16(wp[32]) | ((uint)b16(wp[48]) << 16);
    o.z = (uint)b16(wp[64]) | ((uint)b16(wp[80]) << 16);
    o.w = (uint)b16(wp[96]) | ((uint)b16(wp[112]) << 16);
    ((uint4*)WTb)[g] = o;
  }
}

// ---------------------------------------------------------------------------
// caps_part: block (kc,bgi) = 16 b x 24 k tile (bf16 LDS). Softmax col js,
// then atomicAdd sn[b][u] += sum_k c_k (x[b,k,:]·W[js,k,:,u]).
// Wave w owns k = w*6..+5; lane = (kq 4-way, bq 4 b's, uq 4 u's);
// 2 masked iterations (kli = it*4+kq < 6). 13 KB LDS -> 6 blocks/CU.
// ---------------------------------------------------------------------------
__global__ __launch_bounds__(256, 6) void caps_part(
    const ushort_t* __restrict__ Xb, const ushort_t* __restrict__ WTb,
    const float* __restrict__ bl, float* __restrict__ sn, int js) {
  __shared__ __align__(16) ushort_t sxu[BT * XPH];  // 6400 B [b][k*8+d]
  __shared__ __align__(16) ushort_t swu[KT * WPH];  // 6528 B [k][u*8+d]
  __shared__ float sc[KT];
  float* sred = (float*)sxu;  // aliased after compute (5120 B <= 6400 B)
  const int tid = threadIdx.x;
  const int kc = blockIdx.x % KCN;
  const int bgi = blockIdx.x / KCN;
  const int b0 = bgi * BT;
  const int k0 = kc * KT;

  {  // stage x: 384 uint4
    const uint4* gx = (const uint4*)Xb + ((size_t)b0 * NK + k0);
    for (int i = tid; i < BT * KT; i += 256) {
      const int b = i / KT, q = i - b * KT;
      *(uint4*)&sxu[b * XPH + q * 8] = gx[(size_t)b * NK + q];
    }
  }
  {  // stage w: 384 uint4 (contiguous in WTb)
    const uint4* gw = (const uint4*)WTb + ((size_t)js * NK + k0) * NU;
    for (int i = tid; i < KT * NU; i += 256) {
      const int k = i >> 4, u = i & 15;
      *(uint4*)&swu[k * WPH + u * 8] = gw[i];
    }
  }
  if (tid < KT) {  // softmax of bl row (k0+tid), column js
    const float* row = bl + (size_t)(k0 + tid) * NJ;
    float r[NJ];
#pragma unroll
    for (int jj = 0; jj < NJ; ++jj) r[jj] = row[jj];
    float mx = r[0];
#pragma unroll
    for (int jj = 1; jj < NJ; ++jj) mx = fmaxf(mx, r[jj]);
    float se = 0.f;
#pragma unroll
    for (int jj = 0; jj < NJ; ++jj) se += __expf(r[jj] - mx);
    sc[tid] = __expf(r[js] - mx) / se;
  }
  __syncthreads();

  const int w = tid >> 6;
  const int lane = tid & 63;
  const int kq = lane >> 4;
  const int bq = (lane >> 2) & 3;
  const int uq = lane & 3;
  float a[4][4];
#pragma unroll
  for (int i = 0; i < 4; ++i)
#pragma unroll
    for (int m = 0; m < 4; ++m) a[i][m] = 0.f;

#pragma unroll
  for (int it = 0; it < 2; ++it) {
    const int kli = it * 4 + kq;
    if (kli < 6) {
      const int kl = w * 6 + kli;
      const float ck = sc[kl];
      float xd[4][8];
#pragma unroll
      for (int i = 0; i < 4; ++i)
        up8(*(const uint4*)&sxu[(bq * 4 + i) * XPH + kl * 8], xd[i]);
#pragma unroll
      for (int m = 0; m < 4; ++m) {
        float wd[8];
        up8(*(const uint4*)&swu[kl * WPH + (uq * 4 + m) * 8], wd);
#pragma unroll
        for (int i = 0; i < 4; ++i)
          a[i][m] = fmaf(ck, dot8(xd[i], wd), a[i][m]);
      }
    }
  }
  // reduce over kq (lane bits 4,5)
#pragma unroll
  for (int i = 0; i < 4; ++i)
#pragma unroll
    for (int m = 0; m < 4; ++m) {
      a[i][m] += __shfl_xor(a[i][m], 16, 64);
      a[i][m] += __shfl_xor(a[i][m], 32, 64);
    }
  __syncthreads();  // sx dead; reuse as sred
  if (kq == 0) {
#pragma unroll
    for (int i = 0; i < 4; ++i) {
      const float4 t4 = {a[i][0], a[i][1], a[i][2], a[i][3]};
      *(float4*)&sred[(w * BT + bq * 4 + i) * SREDP + uq * 4] = t4;
    }
  }
  __syncthreads();
  {  // sum 4 waves; accumulate into this phase's s buffer
    const int b = tid >> 4, u = tid & 15;
    const float sv =
        sred[(0 * BT + b) * SREDP + u] + sred[(1 * BT + b) * SREDP + u] +
        sred[(2 * BT + b) * SREDP + u] + sred[(3 * BT + b) * SREDP + u];
    atomicAdd(&sn[(size_t)(b0 + b) * NU + u], sv);
  }
}

// ---------------------------------------------------------------------------
// caps_agp: v = squash(sprev[b]) (1 load/thread; out write from kc==0 when
// wout), then agree for column ja with the same microtile:
// atomicAdd(&bl[k][ja], sum_{b,u} uhat[b,k,u]*v[b,u]).  14.2 KB LDS.
// ---------------------------------------------------------------------------
__global__ __launch_bounds__(256, 6) void caps_agp(
    const ushort_t* __restrict__ Xb, const ushort_t* __restrict__ WTb,
    const float* __restrict__ sprev, float* __restrict__ bl,
    float* __restrict__ out, int ja, int wout) {
  __shared__ __align__(16) ushort_t sxu[BT * XPH];
  __shared__ __align__(16) ushort_t swu[KT * WPH];
  __shared__ float sv[BT * SVP];
  const int tid = threadIdx.x;
  const int kc = blockIdx.x % KCN;
  const int bgi = blockIdx.x / KCN;
  const int b0 = bgi * BT;
  const int k0 = kc * KT;

  {  // stage x
    const uint4* gx = (const uint4*)Xb + ((size_t)b0 * NK + k0);
    for (int i = tid; i < BT * KT; i += 256) {
      const int b = i / KT, q = i - b * KT;
      *(uint4*)&sxu[b * XPH + q * 8] = gx[(size_t)b * NK + q];
    }
  }
  {  // stage w for column ja
    const uint4* gw = (const uint4*)WTb + ((size_t)ja * NK + k0) * NU;
    for (int i = tid; i < KT * NU; i += 256) {
      const int k = i >> 4, u = i & 15;
      *(uint4*)&swu[k * WPH + u * 8] = gw[i];
    }
  }
  {  // v = squash(s); wave = 4b x 16u, u = low 4 lane bits
    const int b = tid >> 4, u = tid & 15;
    const float s = sprev[(size_t)(b0 + b) * NU + u];
    float sq = s * s;
    sq += __shfl_xor(sq, 1, 64);
    sq += __shfl_xor(sq, 2, 64);
    sq += __shfl_xor(sq, 4, 64);
    sq += __shfl_xor(sq, 8, 64);
    const float scale = (sq / (1.f + sq)) / (sqrtf(sq) + EPSQ);
    const float vv = scale * s;
    sv[b * SVP + u] = vv;
    if (wout && kc == 0) out[((size_t)(b0 + b) * NJ + ja) * NU + u] = vv;
  }
  __syncthreads();

  const int w = tid >> 6;
  const int lane = tid & 63;
  const int kq = lane >> 4;
  const int bq = (lane >> 2) & 3;
  const int uq = lane & 3;
  float4 vf[4];  // v fragment [4 b][4 u], const across k
#pragma unroll
  for (int i = 0; i < 4; ++i)
    vf[i] = *(const float4*)&sv[(bq * 4 + i) * SVP + uq * 4];

#pragma unroll
  for (int it = 0; it < 2; ++it) {
    const int kli = it * 4 + kq;
    if (kli < 6) {
      const int kl = w * 6 + kli;
      float xd[4][8];
#pragma unroll
      for (int i = 0; i < 4; ++i)
        up8(*(const uint4*)&sxu[(bq * 4 + i) * XPH + kl * 8], xd[i]);
      float ag = 0.f;
#pragma unroll
      for (int m = 0; m < 4; ++m) {
        float wd[8];
        up8(*(const uint4*)&swu[kl * WPH + (uq * 4 + m) * 8], wd);
#pragma unroll
        for (int i = 0; i < 4; ++i) {
          const float vm = (m == 0) ? vf[i].x
                         : (m == 1) ? vf[i].y
                         : (m == 2) ? vf[i].z : vf[i].w;
          ag = fmaf(vm, dot8(xd[i], wd), ag);
        }
      }
      // reduce over (bq,uq) = lane bits 0-3 (stays within the kq group)
      ag += __shfl_xor(ag, 1, 64);
      ag += __shfl_xor(ag, 2, 64);
      ag += __shfl_xor(ag, 4, 64);
      ag += __shfl_xor(ag, 8, 64);
      if ((lane & 15) == 0)
        atomicAdd(&bl[(size_t)(k0 + kl) * NJ + ja], ag);
    }
  }
}

// ---------------------------------------------------------------------------
// caps_finout: final v for capsule 9 -> out[:, 9, :]  (from phase-29 s)
// ---------------------------------------------------------------------------
__global__ __launch_bounds__(256) void caps_finout(const float* __restrict__ slast,
                                                   float* __restrict__ out) {
  const int g = blockIdx.x * 256 + threadIdx.x;  // 8192
  const int b = g >> 4, u = g & 15;
  const float s = slast[(size_t)b * NU + u];
  float sq = s * s;
  sq += __shfl_xor(sq, 1, 64);
  sq += __shfl_xor(sq, 2, 64);
  sq += __shfl_xor(sq, 4, 64);
  sq += __shfl_xor(sq, 8, 64);
  const float scale = (sq / (1.f + sq)) / (sqrtf(sq) + EPSQ);
  out[((size_t)b * NJ + (NJ - 1)) * NU + u] = scale * s;
}

// ---------------------------------------------------------------------------
extern "C" void kernel_launch(void* const* d_in, const int* in_sizes, int n_in,
                              void* d_out, int out_size, void* d_ws,
                              size_t ws_size, hipStream_t stream) {
  (void)in_sizes; (void)n_in; (void)out_size; (void)ws_size;
  const float* x = (const float*)d_in[0];   // [512][1152][8][1] fp32
  const float* W = (const float*)d_in[1];   // [10][1152][8][16] fp32
  float* out = (float*)d_out;               // [512][10][16][1] fp32
  float* ws = (float*)d_ws;
  float* bl = ws + OFF_BL;
  float* s  = ws + OFF_S;                   // [NPH][NB][NU], zeroed by init
  ushort_t* Xb  = (ushort_t*)(ws + OFF_XB);
  ushort_t* WTb = (ushort_t*)(ws + OFF_WTB);

  caps_init<<<(NB * NK * ND / 8 + 255) / 256, 256, 0, stream>>>(x, W, bl, s,
                                                                Xb, WTb);
  for (int n = 0; n < NPH; ++n) {
    const int j = n / 3, t = n - 3 * j;
    if (n > 0) {
      // agree for phase n-1: capsule ja = (t==0 ? j-1 : j); t==0 also emits
      // the final v of capsule j-1 (kc==0 blocks).
      const int ja = (t == 0) ? (j - 1) : j;
      caps_agp<<<KCN * BGN, 256, 0, stream>>>(
          Xb, WTb, s + (size_t)(n - 1) * NB * NU, bl, out, ja, (t == 0) ? 1 : 0);
    }
    caps_part<<<KCN * BGN, 256, 0, stream>>>(Xb, WTb, bl,
                                             s + (size_t)n * NB * NU, j);
  }
  caps_finout<<<(NB * NU) / 256, 256, 0, stream>>>(
      s + (size_t)(NPH - 1) * NB * NU, out);
}

// Round 14
// 552.791 us; speedup vs baseline: 13.2409x; 2.1762x over previous
//
#include <hip/hip_runtime.h>

typedef unsigned int uint;
typedef unsigned short ushort_t;

#define NB 512      // batch
#define NK 1152     // input capsules
#define ND 8        // in dim
#define NU 16       // out dim
#define NJ 10       // output capsules
#define NPH 30      // routing phases (NJ * 3)
#define EPSQ 1e-7f

#define KT 36       // k per tile (R11 geometry — R13's 24 regressed)
#define KCN 32      // k chunks; kc = blockIdx&31 -> XCD = kc%8
#define BT 16       // b per tile
#define BGN 32      // b groups
#define XPH 296     // x tile pitch per b, bf16 (288+8 pad; bank-verified R11)
#define WPH 136     // w tile pitch per k, bf16 (128+8 pad; bank-verified R11)
#define SREDP 20    // cross-wave reduce pitch (floats)
#define SVP 20      // sv pitch (floats)

// ws layout (floats)
#define OFF_BL 0                        // b_logits [NK][NJ]        11520
#define OFF_P  11520                    // partial [KCN][NB][NU]    262144
#define OFF_XB (OFF_P + KCN*NB*NU)      // Xb bf16 [NB][NK][ND]
#define OFF_WTB (OFF_XB + (NB*NK*ND)/2) // WTb bf16 [NJ][NK][NU][ND]

// fp32 -> bf16 RNE
__device__ __forceinline__ ushort_t b16(float f) {
  uint u = __float_as_uint(f);
  return (ushort_t)((u + 0x7fffu + ((u >> 16) & 1u)) >> 16);
}
__device__ __forceinline__ void up8(const uint4 v, float* f) {
  f[0] = __uint_as_float(v.x << 16); f[1] = __uint_as_float(v.x & 0xffff0000u);
  f[2] = __uint_as_float(v.y << 16); f[3] = __uint_as_float(v.y & 0xffff0000u);
  f[4] = __uint_as_float(v.z << 16); f[5] = __uint_as_float(v.z & 0xffff0000u);
  f[6] = __uint_as_float(v.w << 16); f[7] = __uint_as_float(v.w & 0xffff0000u);
}
__device__ __forceinline__ float dot8(const float* a, const float* b) {
  return a[0]*b[0] + a[1]*b[1] + a[2]*b[2] + a[3]*b[3] +
         a[4]*b[4] + a[5]*b[5] + a[6]*b[6] + a[7]*b[7];
}

// ---------------------------------------------------------------------------
// init: zero bl; build Xb[b][k][d], WTb[j][k][u][d] (bf16).
// partial needs no init: every element is plain-stored by each caps_part.
// ---------------------------------------------------------------------------
__global__ __launch_bounds__(256) void caps_init(const float* __restrict__ x,
                                                 const float* __restrict__ W,
                                                 float* __restrict__ bl,
                                                 ushort_t* __restrict__ Xb,
                                                 ushort_t* __restrict__ WTb) {
  const int g = blockIdx.x * 256 + threadIdx.x;
  if (g < NK * NJ) bl[g] = 0.f;
  if (g < (NB * NK * ND) / 8) {
    const float4* xp = (const float4*)x + (size_t)g * 2;
    const float4 a = xp[0], b = xp[1];
    uint4 o;
    o.x = (uint)b16(a.x) | ((uint)b16(a.y) << 16);
    o.y = (uint)b16(a.z) | ((uint)b16(a.w) << 16);
    o.z = (uint)b16(b.x) | ((uint)b16(b.y) << 16);
    o.w = (uint)b16(b.z) | ((uint)b16(b.w) << 16);
    ((uint4*)Xb)[g] = o;
  }
  if (g < (NJ * NK * NU * ND) / 8) {
    const int u = g & 15;
    const int k = (g >> 4) % NK;
    const int j = g / (NK * NU);
    const float* wp = W + ((size_t)(j * NK + k) * ND) * NU + u;
    uint4 o;
    o.x = (uint)b16(wp[0])  | ((uint)b16(wp[16]) << 16);
    o.y = (uint)b16(wp[32]) | ((uint)b16(wp[48]) << 16);
    o.z = (uint)b16(wp[64]) | ((uint)b16(wp[80]) << 16);
    o.w = (uint)b16(wp[96]) | ((uint)b16(wp[112]) << 16);
    ((uint4*)WTb)[g] = o;
  }
}

// ---------------------------------------------------------------------------
// caps_part: block (kc,bgi) = 16 b x 36 k tile (bf16 LDS). Softmax col js,
// then PLAIN-STORE partial[kc][b][u] = sum_{k in tile} c_k (x·W[js]).
// (R14: atomics removed — they cost ~200 B HBM RMW each, R13 post-mortem.)
// ---------------------------------------------------------------------------
__global__ __launch_bounds__(256, 4) void caps_part(
    const ushort_t* __restrict__ Xb, const ushort_t* __restrict__ WTb,
    const float* __restrict__ bl, float* __restrict__ partial, int js) {
  __shared__ __align__(16) ushort_t sxu[BT * XPH];  // 9472 B [b][k*8+d]
  __shared__ __align__(16) ushort_t swu[KT * WPH];  // 9792 B [k][u*8+d]
  __shared__ float sc[KT];
  float* sred = (float*)sxu;  // aliased after compute (5120 B, barrier-guarded)
  const int tid = threadIdx.x;
  const int kc = blockIdx.x & (KCN - 1);
  const int bgi = blockIdx.x >> 5;
  const int b0 = bgi * BT;
  const int k0 = kc * KT;

  {  // stage x: 576 uint4
    const uint4* gx = (const uint4*)Xb + ((size_t)b0 * NK + k0);
    for (int i = tid; i < BT * KT; i += 256) {
      const int b = i / KT, q = i - b * KT;
      *(uint4*)&sxu[b * XPH + q * 8] = gx[(size_t)b * NK + q];
    }
  }
  {  // stage w: 576 uint4 (contiguous in WTb)
    const uint4* gw = (const uint4*)WTb + ((size_t)js * NK + k0) * NU;
    for (int i = tid; i < KT * NU; i += 256) {
      const int k = i >> 4, u = i & 15;
      *(uint4*)&swu[k * WPH + u * 8] = gw[i];
    }
  }
  if (tid < KT) {  // softmax of bl row (k0+tid), column js
    const float* row = bl + (size_t)(k0 + tid) * NJ;
    float r[NJ];
#pragma unroll
    for (int jj = 0; jj < NJ; ++jj) r[jj] = row[jj];
    float mx = r[0];
#pragma unroll
    for (int jj = 1; jj < NJ; ++jj) mx = fmaxf(mx, r[jj]);
    float se = 0.f;
#pragma unroll
    for (int jj = 0; jj < NJ; ++jj) se += __expf(r[jj] - mx);
    sc[tid] = __expf(r[js] - mx) / se;
  }
  __syncthreads();

  const int w = tid >> 6;
  const int lane = tid & 63;
  const int kq = lane >> 4;
  const int bq = (lane >> 2) & 3;
  const int uq = lane & 3;
  float a[4][4];
#pragma unroll
  for (int i = 0; i < 4; ++i)
#pragma unroll
    for (int m = 0; m < 4; ++m) a[i][m] = 0.f;

#pragma unroll
  for (int it = 0; it < 3; ++it) {
    const int kli = it * 4 + kq;
    if (kli < 9) {
      const int kl = w * 9 + kli;
      const float ck = sc[kl];
      float xd[4][8];
#pragma unroll
      for (int i = 0; i < 4; ++i)
        up8(*(const uint4*)&sxu[(bq * 4 + i) * XPH + kl * 8], xd[i]);
#pragma unroll
      for (int m = 0; m < 4; ++m) {
        float wd[8];
        up8(*(const uint4*)&swu[kl * WPH + (uq * 4 + m) * 8], wd);
#pragma unroll
        for (int i = 0; i < 4; ++i)
          a[i][m] = fmaf(ck, dot8(xd[i], wd), a[i][m]);
      }
    }
  }
  // reduce over kq (lane bits 4,5)
#pragma unroll
  for (int i = 0; i < 4; ++i)
#pragma unroll
    for (int m = 0; m < 4; ++m) {
      a[i][m] += __shfl_xor(a[i][m], 16, 64);
      a[i][m] += __shfl_xor(a[i][m], 32, 64);
    }
  __syncthreads();  // sx dead; reuse as sred
  if (kq == 0) {
#pragma unroll
    for (int i = 0; i < 4; ++i) {
      const float4 t4 = {a[i][0], a[i][1], a[i][2], a[i][3]};
      *(float4*)&sred[(w * BT + bq * 4 + i) * SREDP + uq * 4] = t4;
    }
  }
  __syncthreads();
  {  // sum 4 waves; PLAIN coalesced store of this kc's partial
    const int b = tid >> 4, u = tid & 15;
    const float sv =
        sred[(0 * BT + b) * SREDP + u] + sred[(1 * BT + b) * SREDP + u] +
        sred[(2 * BT + b) * SREDP + u] + sred[(3 * BT + b) * SREDP + u];
    partial[(size_t)kc * (NB * NU) + (size_t)(b0 + b) * NU + u] = sv;
  }
}

// ---------------------------------------------------------------------------
// caps_agp: v = squash(sum_kc partial[.][b][u]) (32 coalesced loads/thread,
// plain cacheable — NOT atomics), out write from kc==0 when wout, then agree
// for column ja with the 4b x 4u x kq microtile:
// atomicAdd(&bl[k][ja], ...) — kept: only ~37K small atomics/dispatch.
// ---------------------------------------------------------------------------
__global__ __launch_bounds__(256, 4) void caps_agp(
    const ushort_t* __restrict__ Xb, const ushort_t* __restrict__ WTb,
    const float* __restrict__ partial, float* __restrict__ bl,
    float* __restrict__ out, int ja, int wout) {
  __shared__ __align__(16) ushort_t sxu[BT * XPH];
  __shared__ __align__(16) ushort_t swu[KT * WPH];
  __shared__ float sv[BT * SVP];
  const int tid = threadIdx.x;
  const int kc = blockIdx.x & (KCN - 1);
  const int bgi = blockIdx.x >> 5;
  const int b0 = bgi * BT;
  const int k0 = kc * KT;

  {  // stage x
    const uint4* gx = (const uint4*)Xb + ((size_t)b0 * NK + k0);
    for (int i = tid; i < BT * KT; i += 256) {
      const int b = i / KT, q = i - b * KT;
      *(uint4*)&sxu[b * XPH + q * 8] = gx[(size_t)b * NK + q];
    }
  }
  {  // stage w for column ja
    const uint4* gw = (const uint4*)WTb + ((size_t)ja * NK + k0) * NU;
    for (int i = tid; i < KT * NU; i += 256) {
      const int k = i >> 4, u = i & 15;
      *(uint4*)&swu[k * WPH + u * 8] = gw[i];
    }
  }
  {  // v = squash(sum of KCN partials); wave = 4b x 16u, u = low 4 lane bits
    const int b = tid >> 4, u = tid & 15;
    const float* pp = partial + (size_t)(b0 + b) * NU + u;
    float s = 0.f;
#pragma unroll
    for (int c = 0; c < KCN; ++c) s += pp[(size_t)c * (NB * NU)];
    float sq = s * s;
    sq += __shfl_xor(sq, 1, 64);
    sq += __shfl_xor(sq, 2, 64);
    sq += __shfl_xor(sq, 4, 64);
    sq += __shfl_xor(sq, 8, 64);
    const float scale = (sq / (1.f + sq)) / (sqrtf(sq) + EPSQ);
    const float vv = scale * s;
    sv[b * SVP + u] = vv;
    if (wout && kc == 0) out[((size_t)(b0 + b) * NJ + ja) * NU + u] = vv;
  }
  __syncthreads();

  const int w = tid >> 6;
  const int lane = tid & 63;
  const int kq = lane >> 4;
  const int bq = (lane >> 2) & 3;
  const int uq = lane & 3;
  float4 vf[4];  // v fragment [4 b][4 u], const across k
#pragma unroll
  for (int i = 0; i < 4; ++i)
    vf[i] = *(const float4*)&sv[(bq * 4 + i) * SVP + uq * 4];

#pragma unroll
  for (int it = 0; it < 3; ++it) {
    const int kli = it * 4 + kq;
    if (kli < 9) {
      const int kl = w * 9 + kli;
      float xd[4][8];
#pragma unroll
      for (int i = 0; i < 4; ++i)
        up8(*(const uint4*)&sxu[(bq * 4 + i) * XPH + kl * 8], xd[i]);
      float ag = 0.f;
#pragma unroll
      for (int m = 0; m < 4; ++m) {
        float wd[8];
        up8(*(const uint4*)&swu[kl * WPH + (uq * 4 + m) * 8], wd);
#pragma unroll
        for (int i = 0; i < 4; ++i) {
          const float vm = (m == 0) ? vf[i].x
                         : (m == 1) ? vf[i].y
                         : (m == 2) ? vf[i].z : vf[i].w;
          ag = fmaf(vm, dot8(xd[i], wd), ag);
        }
      }
      // reduce over (bq,uq) = lane bits 0-3 (stays within the kq group)
      ag += __shfl_xor(ag, 1, 64);
      ag += __shfl_xor(ag, 2, 64);
      ag += __shfl_xor(ag, 4, 64);
      ag += __shfl_xor(ag, 8, 64);
      if ((lane & 15) == 0)
        atomicAdd(&bl[(size_t)(k0 + kl) * NJ + ja], ag);
    }
  }
}

// ---------------------------------------------------------------------------
// caps_finout: final v for capsule 9 -> out[:, 9, :] (sums KCN partials)
// ---------------------------------------------------------------------------
__global__ __launch_bounds__(256) void caps_finout(const float* __restrict__ partial,
                                                   float* __restrict__ out) {
  const int g = blockIdx.x * 256 + threadIdx.x;  // 8192
  const int b = g >> 4, u = g & 15;
  float s = 0.f;
#pragma unroll
  for (int c = 0; c < KCN; ++c)
    s += partial[(size_t)c * (NB * NU) + (size_t)b * NU + u];
  float sq = s * s;
  sq += __shfl_xor(sq, 1, 64);
  sq += __shfl_xor(sq, 2, 64);
  sq += __shfl_xor(sq, 4, 64);
  sq += __shfl_xor(sq, 8, 64);
  const float scale = (sq / (1.f + sq)) / (sqrtf(sq) + EPSQ);
  out[((size_t)b * NJ + (NJ - 1)) * NU + u] = scale * s;
}

// ---------------------------------------------------------------------------
extern "C" void kernel_launch(void* const* d_in, const int* in_sizes, int n_in,
                              void* d_out, int out_size, void* d_ws,
                              size_t ws_size, hipStream_t stream) {
  (void)in_sizes; (void)n_in; (void)out_size; (void)ws_size;
  const float* x = (const float*)d_in[0];   // [512][1152][8][1] fp32
  const float* W = (const float*)d_in[1];   // [10][1152][8][16] fp32
  float* out = (float*)d_out;               // [512][10][16][1] fp32
  float* ws = (float*)d_ws;
  float* bl = ws + OFF_BL;
  float* pt = ws + OFF_P;                   // fully overwritten each phase
  ushort_t* Xb  = (ushort_t*)(ws + OFF_XB);
  ushort_t* WTb = (ushort_t*)(ws + OFF_WTB);

  caps_init<<<(NB * NK * ND / 8 + 255) / 256, 256, 0, stream>>>(x, W, bl, Xb,
                                                                WTb);
  for (int n = 0; n < NPH; ++n) {
    const int j = n / 3, t = n - 3 * j;
    if (n > 0) {
      // agree for phase n-1: capsule ja = (t==0 ? j-1 : j); t==0 also emits
      // the final v of capsule j-1 (kc==0 blocks).
      const int ja = (t == 0) ? (j - 1) : j;
      caps_agp<<<KCN * BGN, 256, 0, stream>>>(Xb, WTb, pt, bl, out, ja,
                                              (t == 0) ? 1 : 0);
    }
    caps_part<<<KCN * BGN, 256, 0, stream>>>(Xb, WTb, bl, pt, j);
  }
  caps_finout<<<(NB * NU) / 256, 256, 0, stream>>>(pt, out);
}

// Round 15
// 519.358 us; speedup vs baseline: 14.0932x; 1.0644x over previous
//
#include <hip/hip_runtime.h>

typedef unsigned int uint;
typedef unsigned short ushort_t;

#define NB 512      // batch
#define NK 1152     // input capsules
#define ND 8        // in dim
#define NU 16       // out dim
#define NJ 10       // output capsules
#define NPH 30      // routing phases (NJ * 3)
#define EPSQ 1e-7f

#define KT 36       // k per tile (R11 geometry)
#define KCN 32      // k chunks; kc = blockIdx&31 -> XCD = kc%8
#define BT 16       // b per tile
#define BGN 32      // b groups
#define XPH 296     // x tile pitch per b, bf16 (288+8 pad; bank-verified R11)
#define WPH 136     // w tile pitch per k, bf16 (128+8 pad; bank-verified R11)
#define SREDP 20    // cross-wave reduce pitch (floats)
#define SVP 20      // sv pitch (floats)

// ws layout (floats)
#define OFF_BLA 0                        // blA [NK][NJ]  (zeroed)
#define OFF_BLB (NK*NJ)                  // blB [NK][NJ]  (fully written ph.0)
#define OFF_AGP (2*NK*NJ)                // agp_p [NK][BGN]       36864
#define OFF_S   (OFF_AGP + NK*BGN)       // s [NPH][NB][NU]       245760
#define OFF_XB  (OFF_S + NPH*NB*NU)      // Xb bf16 [NB][NK][ND]
#define OFF_WTB (OFF_XB + (NB*NK*ND)/2)  // WTb bf16 [NJ][NK][NU][ND]

// fp32 -> bf16 RNE
__device__ __forceinline__ ushort_t b16(float f) {
  uint u = __float_as_uint(f);
  return (ushort_t)((u + 0x7fffu + ((u >> 16) & 1u)) >> 16);
}
__device__ __forceinline__ void up8(const uint4 v, float* f) {
  f[0] = __uint_as_float(v.x << 16); f[1] = __uint_as_float(v.x & 0xffff0000u);
  f[2] = __uint_as_float(v.y << 16); f[3] = __uint_as_float(v.y & 0xffff0000u);
  f[4] = __uint_as_float(v.z << 16); f[5] = __uint_as_float(v.z & 0xffff0000u);
  f[6] = __uint_as_float(v.w << 16); f[7] = __uint_as_float(v.w & 0xffff0000u);
}
__device__ __forceinline__ float dot8(const float* a, const float* b) {
  return a[0]*b[0] + a[1]*b[1] + a[2]*b[2] + a[3]*b[3] +
         a[4]*b[4] + a[5]*b[5] + a[6]*b[6] + a[7]*b[7];
}

// ---------------------------------------------------------------------------
// init: zero blA + s; build Xb[b][k][d], WTb[j][k][u][d] (bf16)
// ---------------------------------------------------------------------------
__global__ __launch_bounds__(256) void caps_init(const float* __restrict__ x,
                                                 const float* __restrict__ W,
                                                 float* __restrict__ blA,
                                                 float* __restrict__ s,
                                                 ushort_t* __restrict__ Xb,
                                                 ushort_t* __restrict__ WTb) {
  const int g = blockIdx.x * 256 + threadIdx.x;
  if (g < NK * NJ) blA[g] = 0.f;
  if (g < NPH * NB * NU) s[g] = 0.f;
  if (g < (NB * NK * ND) / 8) {
    const float4* xp = (const float4*)x + (size_t)g * 2;
    const float4 a = xp[0], b = xp[1];
    uint4 o;
    o.x = (uint)b16(a.x) | ((uint)b16(a.y) << 16);
    o.y = (uint)b16(a.z) | ((uint)b16(a.w) << 16);
    o.z = (uint)b16(b.x) | ((uint)b16(b.y) << 16);
    o.w = (uint)b16(b.z) | ((uint)b16(b.w) << 16);
    ((uint4*)Xb)[g] = o;
  }
  if (g < (NJ * NK * NU * ND) / 8) {
    const int u = g & 15;
    const int k = (g >> 4) % NK;
    const int j = g / (NK * NU);
    const float* wp = W + ((size_t)(j * NK + k) * ND) * NU + u;
    uint4 o;
    o.x = (uint)b16(wp[0])  | ((uint)b16(wp[16]) << 16);
    o.y = (uint)b16(wp[32]) | ((uint)b16(wp[48]) << 16);
    o.z = (uint)b16(wp[64]) | ((uint)b16(wp[80]) << 16);
    o.w = (uint)b16(wp[96]) | ((uint)b16(wp[112]) << 16);
    ((uint4*)WTb)[g] = o;
  }
}

// ---------------------------------------------------------------------------
// caps_part: block (kc,bgi) = 16 b x 36 k tile (bf16 LDS).
// Softmax: r = blIn row; r[jaPrev] += sum_bgi agp_p[k][*] (phase n-1 agree,
// plain reads — replaces R11's bl atomics); bgi==0 stores r -> blOut
// (ping-pong: blIn stable all dispatch, duplicate stores value-identical).
// Then atomicAdd sn[b][u] += sum_{k in tile} c_k (x·W[js])  [R11-proven].
// ---------------------------------------------------------------------------
__global__ __launch_bounds__(256, 4) void caps_part(
    const ushort_t* __restrict__ Xb, const ushort_t* __restrict__ WTb,
    const float* __restrict__ blIn, float* __restrict__ blOut,
    const float* __restrict__ agp_p, float* __restrict__ sn, int js,
    int jaPrev) {
  __shared__ __align__(16) ushort_t sxu[BT * XPH];  // 9472 B [b][k*8+d]
  __shared__ __align__(16) ushort_t swu[KT * WPH];  // 9792 B [k][u*8+d]
  __shared__ float sc[KT];
  float* sred = (float*)sxu;  // aliased after compute (5120 B, barrier-guarded)
  const int tid = threadIdx.x;
  const int kc = blockIdx.x & (KCN - 1);
  const int bgi = blockIdx.x >> 5;
  const int b0 = bgi * BT;
  const int k0 = kc * KT;

  {  // stage x: 576 uint4
    const uint4* gx = (const uint4*)Xb + ((size_t)b0 * NK + k0);
    for (int i = tid; i < BT * KT; i += 256) {
      const int b = i / KT, q = i - b * KT;
      *(uint4*)&sxu[b * XPH + q * 8] = gx[(size_t)b * NK + q];
    }
  }
  {  // stage w: 576 uint4 (contiguous in WTb)
    const uint4* gw = (const uint4*)WTb + ((size_t)js * NK + k0) * NU;
    for (int i = tid; i < KT * NU; i += 256) {
      const int k = i >> 4, u = i & 15;
      *(uint4*)&swu[k * WPH + u * 8] = gw[i];
    }
  }
  if (tid < KT) {  // reconstruct bl row (k0+tid), persist, softmax col js
    const int k = k0 + tid;
    const float* rowIn = blIn + (size_t)k * NJ;
    float r[NJ];
#pragma unroll
    for (int jj = 0; jj < NJ; ++jj) r[jj] = rowIn[jj];
    if (jaPrev >= 0) {  // fold phase n-1 agree: sum 32 per-bgi partials
      const float4* ap = (const float4*)(agp_p + (size_t)k * BGN);
      float agsum = 0.f;
#pragma unroll
      for (int i = 0; i < BGN / 4; ++i) {
        const float4 t4 = ap[i];
        agsum += t4.x + t4.y + t4.z + t4.w;
      }
      r[jaPrev] += agsum;
    }
    if (bgi == 0) {  // one kc-column of blocks persists the updated rows
      float* rowOut = blOut + (size_t)k * NJ;
#pragma unroll
      for (int jj = 0; jj < NJ; ++jj) rowOut[jj] = r[jj];
    }
    float mx = r[0];
#pragma unroll
    for (int jj = 1; jj < NJ; ++jj) mx = fmaxf(mx, r[jj]);
    float se = 0.f;
#pragma unroll
    for (int jj = 0; jj < NJ; ++jj) se += __expf(r[jj] - mx);
    sc[tid] = __expf(r[js] - mx) / se;
  }
  __syncthreads();

  const int w = tid >> 6;
  const int lane = tid & 63;
  const int kq = lane >> 4;
  const int bq = (lane >> 2) & 3;
  const int uq = lane & 3;
  float a[4][4];
#pragma unroll
  for (int i = 0; i < 4; ++i)
#pragma unroll
    for (int m = 0; m < 4; ++m) a[i][m] = 0.f;

#pragma unroll
  for (int it = 0; it < 3; ++it) {
    const int kli = it * 4 + kq;
    if (kli < 9) {
      const int kl = w * 9 + kli;
      const float ck = sc[kl];
      float xd[4][8];
#pragma unroll
      for (int i = 0; i < 4; ++i)
        up8(*(const uint4*)&sxu[(bq * 4 + i) * XPH + kl * 8], xd[i]);
#pragma unroll
      for (int m = 0; m < 4; ++m) {
        float wd[8];
        up8(*(const uint4*)&swu[kl * WPH + (uq * 4 + m) * 8], wd);
#pragma unroll
        for (int i = 0; i < 4; ++i)
          a[i][m] = fmaf(ck, dot8(xd[i], wd), a[i][m]);
      }
    }
  }
  // reduce over kq (lane bits 4,5)
#pragma unroll
  for (int i = 0; i < 4; ++i)
#pragma unroll
    for (int m = 0; m < 4; ++m) {
      a[i][m] += __shfl_xor(a[i][m], 16, 64);
      a[i][m] += __shfl_xor(a[i][m], 32, 64);
    }
  __syncthreads();  // sx dead; reuse as sred
  if (kq == 0) {
#pragma unroll
    for (int i = 0; i < 4; ++i) {
      const float4 t4 = {a[i][0], a[i][1], a[i][2], a[i][3]};
      *(float4*)&sred[(w * BT + bq * 4 + i) * SREDP + uq * 4] = t4;
    }
  }
  __syncthreads();
  {  // sum 4 waves; atomic-accumulate into phase s buffer (R11-measured best)
    const int b = tid >> 4, u = tid & 15;
    const float sv =
        sred[(0 * BT + b) * SREDP + u] + sred[(1 * BT + b) * SREDP + u] +
        sred[(2 * BT + b) * SREDP + u] + sred[(3 * BT + b) * SREDP + u];
    atomicAdd(&sn[(size_t)(b0 + b) * NU + u], sv);
  }
}

// ---------------------------------------------------------------------------
// caps_agp: v = squash(sprev[b]) (1 load/thread; out write from kc==0 when
// wout), then agree for column ja with the 4b x 4u x kq microtile;
// plain-store agp_p[k][bgi] (R15: replaces bl atomicAdd).
// ---------------------------------------------------------------------------
__global__ __launch_bounds__(256, 4) void caps_agp(
    const ushort_t* __restrict__ Xb, const ushort_t* __restrict__ WTb,
    const float* __restrict__ sprev, float* __restrict__ agp_p,
    float* __restrict__ out, int ja, int wout) {
  __shared__ __align__(16) ushort_t sxu[BT * XPH];
  __shared__ __align__(16) ushort_t swu[KT * WPH];
  __shared__ float sv[BT * SVP];
  const int tid = threadIdx.x;
  const int kc = blockIdx.x & (KCN - 1);
  const int bgi = blockIdx.x >> 5;
  const int b0 = bgi * BT;
  const int k0 = kc * KT;

  {  // stage x
    const uint4* gx = (const uint4*)Xb + ((size_t)b0 * NK + k0);
    for (int i = tid; i < BT * KT; i += 256) {
      const int b = i / KT, q = i - b * KT;
      *(uint4*)&sxu[b * XPH + q * 8] = gx[(size_t)b * NK + q];
    }
  }
  {  // stage w for column ja
    const uint4* gw = (const uint4*)WTb + ((size_t)ja * NK + k0) * NU;
    for (int i = tid; i < KT * NU; i += 256) {
      const int k = i >> 4, u = i & 15;
      *(uint4*)&swu[k * WPH + u * 8] = gw[i];
    }
  }
  {  // v = squash(s) from the atomically-accumulated phase buffer
    const int b = tid >> 4, u = tid & 15;   // u = lane bits 0-3
    const float s = sprev[(size_t)(b0 + b) * NU + u];
    float sq = s * s;
    sq += __shfl_xor(sq, 1, 64);
    sq += __shfl_xor(sq, 2, 64);
    sq += __shfl_xor(sq, 4, 64);
    sq += __shfl_xor(sq, 8, 64);
    const float scale = (sq / (1.f + sq)) / (sqrtf(sq) + EPSQ);
    const float vv = scale * s;
    sv[b * SVP + u] = vv;
    if (wout && kc == 0) out[((size_t)(b0 + b) * NJ + ja) * NU + u] = vv;
  }
  __syncthreads();

  const int w = tid >> 6;
  const int lane = tid & 63;
  const int kq = lane >> 4;
  const int bq = (lane >> 2) & 3;
  const int uq = lane & 3;
  float4 vf[4];  // v fragment [4 b][4 u], const across k
#pragma unroll
  for (int i = 0; i < 4; ++i)
    vf[i] = *(const float4*)&sv[(bq * 4 + i) * SVP + uq * 4];

#pragma unroll
  for (int it = 0; it < 3; ++it) {
    const int kli = it * 4 + kq;
    if (kli < 9) {
      const int kl = w * 9 + kli;
      float xd[4][8];
#pragma unroll
      for (int i = 0; i < 4; ++i)
        up8(*(const uint4*)&sxu[(bq * 4 + i) * XPH + kl * 8], xd[i]);
      float ag = 0.f;
#pragma unroll
      for (int m = 0; m < 4; ++m) {
        float wd[8];
        up8(*(const uint4*)&swu[kl * WPH + (uq * 4 + m) * 8], wd);
#pragma unroll
        for (int i = 0; i < 4; ++i) {
          const float vm = (m == 0) ? vf[i].x
                         : (m == 1) ? vf[i].y
                         : (m == 2) ? vf[i].z : vf[i].w;
          ag = fmaf(vm, dot8(xd[i], wd), ag);
        }
      }
      // reduce over (bq,uq) = lane bits 0-3 (stays within the kq group):
      // lane kq*16 then holds this block's agree sum for k = w*9+kli
      ag += __shfl_xor(ag, 1, 64);
      ag += __shfl_xor(ag, 2, 64);
      ag += __shfl_xor(ag, 4, 64);
      ag += __shfl_xor(ag, 8, 64);
      if ((lane & 15) == 0)  // plain store, no atomic (R15)
        agp_p[(size_t)(k0 + kl) * BGN + bgi] = ag;
    }
  }
}

// ---------------------------------------------------------------------------
// caps_finout: final v for capsule 9 -> out[:, 9, :]  (from phase-29 s)
// ---------------------------------------------------------------------------
__global__ __launch_bounds__(256) void caps_finout(const float* __restrict__ slast,
                                                   float* __restrict__ out) {
  const int g = blockIdx.x * 256 + threadIdx.x;  // 8192
  const int b = g >> 4, u = g & 15;
  const float s = slast[(size_t)b * NU + u];
  float sq = s * s;
  sq += __shfl_xor(sq, 1, 64);
  sq += __shfl_xor(sq, 2, 64);
  sq += __shfl_xor(sq, 4, 64);
  sq += __shfl_xor(sq, 8, 64);
  const float scale = (sq / (1.f + sq)) / (sqrtf(sq) + EPSQ);
  out[((size_t)b * NJ + (NJ - 1)) * NU + u] = scale * s;
}

// ---------------------------------------------------------------------------
extern "C" void kernel_launch(void* const* d_in, const int* in_sizes, int n_in,
                              void* d_out, int out_size, void* d_ws,
                              size_t ws_size, hipStream_t stream) {
  (void)in_sizes; (void)n_in; (void)out_size; (void)ws_size;
  const float* x = (const float*)d_in[0];   // [512][1152][8][1] fp32
  const float* W = (const float*)d_in[1];   // [10][1152][8][16] fp32
  float* out = (float*)d_out;               // [512][10][16][1] fp32
  float* ws = (float*)d_ws;
  float* blA = ws + OFF_BLA;                // zeroed by init
  float* blB = ws + OFF_BLB;                // fully written by part(0)
  float* agp = ws + OFF_AGP;
  float* s   = ws + OFF_S;                  // [NPH][NB][NU], zeroed by init
  ushort_t* Xb  = (ushort_t*)(ws + OFF_XB);
  ushort_t* WTb = (ushort_t*)(ws + OFF_WTB);

  caps_init<<<(NB * NK * ND / 8 + 255) / 256, 256, 0, stream>>>(x, W, blA, s,
                                                                Xb, WTb);
  for (int n = 0; n < NPH; ++n) {
    const int j = n / 3, t = n - 3 * j;
    // agree column for phase n-1 (t==0 folds prev capsule's last update and
    // emits its final v); part(n) folds agp_p into the same column.
    const int ja = (t == 0) ? (j - 1) : j;
    if (n > 0)
      caps_agp<<<KCN * BGN, 256, 0, stream>>>(
          Xb, WTb, s + (size_t)(n - 1) * NB * NU, agp, out, ja,
          (t == 0) ? 1 : 0);
    float* bin  = (n & 1) ? blB : blA;
    float* bout = (n & 1) ? blA : blB;
    caps_part<<<KCN * BGN, 256, 0, stream>>>(Xb, WTb, bin, bout, agp,
                                             s + (size_t)n * NB * NU, j,
                                             (n > 0) ? ja : -1);
  }
  caps_finout<<<(NB * NU) / 256, 256, 0, stream>>>(
      s + (size_t)(NPH - 1) * NB * NU, out);
}